// Round 11
// baseline (183.482 us; speedup 1.0000x reference)
//
#include <hip/hip_runtime.h>
#include <hip/hip_bf16.h>

#define D 128
#define EDGE_DIM 6
#define LN_EPS 1e-5f
#define HIST_BLOCKS 2048

typedef __attribute__((ext_vector_type(8))) short short8;
typedef __attribute__((ext_vector_type(4))) float f32x4;
typedef __attribute__((ext_vector_type(2))) float f32x2;

static __device__ __forceinline__ float bf_lo(unsigned u) { return __uint_as_float(u << 16); }
static __device__ __forceinline__ float bf_hi(unsigned u) { return __uint_as_float(u & 0xffff0000u); }
static __device__ __forceinline__ unsigned short f2bf(float f) {
    __hip_bfloat16 h = __float2bfloat16(f);
    return *reinterpret_cast<unsigned short*>(&h);
}
// d = a.bf16[0]*b.bf16[0] + a.bf16[1]*b.bf16[1] + c
static __device__ __forceinline__ float dot2bf(unsigned a, unsigned b, float c) {
    float d;
    asm("v_dot2_f32_bf16 %0, %1, %2, %3" : "=v"(d) : "v"(a), "v"(b), "v"(c));
    return d;
}
// decode 2 fp8 (e4m3, low 16 bits of w) -> 2 f32
static __device__ __forceinline__ f32x2 cvt2_fp8(unsigned w) {
    f32x2 r;
    asm("v_cvt_pk_f32_fp8 %0, %1" : "=v"(r) : "v"(w));
    return r;
}
// encode f32 -> 1 fp8 byte
static __device__ __forceinline__ unsigned f2fp8(float f) {
    unsigned u;
    asm("v_cvt_pk_fp8_f32 %0, %1, %2" : "=v"(u) : "v"(f), "v"(0.0f));
    return u & 0xffu;
}

// ---------- kernel 1: fused setup ----------
// blocks 0..127: Wnm = Wn@Wm1 ; 128: bnm = bn@Wm1 ; 129..134: Wc = We@Wm2 ;
// 135: bc = be@Wm2 + bm ; >=136: histogram of edge rows.
__global__ __launch_bounds__(128)
void setup_all(const float* __restrict__ Wn, const float* __restrict__ bn,
               const float* __restrict__ We, const float* __restrict__ be,
               const float* __restrict__ Wm, const float* __restrict__ bm,
               const int* __restrict__ ei, int E,
               float* __restrict__ Wnm, float* __restrict__ bnm,
               float* __restrict__ Wc, float* __restrict__ bc,
               int* __restrict__ cnt) {
    const int b = blockIdx.x;
    const int d = threadIdx.x;
    if (b < 128) {
        float acc = 0.f;
#pragma unroll 8
        for (int j = 0; j < D; ++j)
            acc = fmaf(Wn[b * D + j], Wm[j * D + d], acc);
        Wnm[b * D + d] = acc;
    } else if (b == 128) {
        float acc = 0.f;
#pragma unroll 8
        for (int j = 0; j < D; ++j)
            acc = fmaf(bn[j], Wm[j * D + d], acc);
        bnm[d] = acc;
    } else if (b < 135) {
        const int k = b - 129;
        float acc = 0.f;
#pragma unroll 8
        for (int j = 0; j < D; ++j)
            acc = fmaf(We[k * D + j], Wm[(D + j) * D + d], acc);
        Wc[k * D + d] = acc;
    } else if (b == 135) {
        float acc = bm[d];
#pragma unroll 8
        for (int j = 0; j < D; ++j)
            acc = fmaf(be[j], Wm[(D + j) * D + d], acc);
        bc[d] = acc;
    } else {
        for (int i = (b - 136) * 128 + d; i < E; i += HIST_BLOCKS * 128)
            atomicAdd(&cnt[ei[i]], 1);
    }
}

// ---------- kernel 2: scan (blocks < nscan) + pack Wb (blocks >= nscan) ----------
__global__ __launch_bounds__(1024)
void scan_pack(const int* __restrict__ cnt, int* __restrict__ start,
               int* __restrict__ cur, int* __restrict__ cursor, int n, int nscan,
               const float* __restrict__ Wn, const float* __restrict__ Wnm,
               unsigned short* __restrict__ Wb) {
    const int tid = threadIdx.x;
    if ((int)blockIdx.x >= nscan) {
        const int idx = ((int)blockIdx.x - nscan) * 1024 + tid;  // 4096 fragments
        if (idx < 4096) {
            const int lane = idx & 63;
            const int s = (idx >> 6) & 3;
            const int ct = (idx >> 8) & 7;
            const int mat = idx >> 11;
            const float* W = mat ? Wnm : Wn;
            const int col = ct * 16 + (lane & 15);
            const int k0 = (lane >> 4) * 8 + 32 * s;
            short8 v;
#pragma unroll
            for (int j = 0; j < 8; ++j)
                v[j] = (short)f2bf(W[(size_t)(k0 + j) * D + col]);
            *reinterpret_cast<short8*>(Wb + (size_t)idx * 8) = v;
        }
        return;
    }
    __shared__ int wsum[16];
    __shared__ int sbase;
    const int lane = tid & 63, wid = tid >> 6;
    const int i = blockIdx.x * 1024 + tid;
    const int v = (i < n) ? cnt[i] : 0;
    int x = v;
#pragma unroll
    for (int off = 1; off < 64; off <<= 1) {
        int t = __shfl_up(x, off);
        if (lane >= off) x += t;
    }
    if (lane == 63) wsum[wid] = x;
    __syncthreads();
    if (wid == 0) {
        int w = (lane < 16) ? wsum[lane] : 0;
#pragma unroll
        for (int off = 1; off < 16; off <<= 1) {
            int t = __shfl_up(w, off);
            if (lane >= off) w += t;
        }
        if (lane < 16) wsum[lane] = w;
    }
    __syncthreads();
    const int total = wsum[15];
    if (tid == 0) sbase = atomicAdd(cursor, total);
    __syncthreads();
    const int woff = (wid > 0) ? wsum[wid - 1] : 0;
    if (i < n) {
        const int sv = sbase + woff + x - v;
        start[i] = sv;
        cur[i] = sv;
    }
}

// ---------- kernel 3: scatter CSR records, 8 edges/thread, batched atomics ----------
__global__ __launch_bounds__(256)
void scatter_rec(const int* __restrict__ ei, int E, const float* __restrict__ ea,
                 int* __restrict__ cur, uint4* __restrict__ rec) {
    __shared__ unsigned sR[2048 * 3];  // 24 KB: (b01,b23,b45) per edge
    const int tid = threadIdx.x;
    const int base = blockIdx.x * 2048;
    const int nrec = min(2048, E - base);
    const float2* ea2 = reinterpret_cast<const float2*>(ea);
    for (int i = tid; i < nrec * 3; i += 256) {
        float2 p = ea2[(size_t)base * 3 + i];
        sR[i] = (unsigned)f2bf(p.x) | ((unsigned)f2bf(p.y) << 16);
    }
    __syncthreads();

    int rows[8], cols[8], pos[8];
#pragma unroll
    for (int it = 0; it < 8; ++it) {
        const int e = base + it * 256 + tid;
        const bool val = e < E;
        rows[it] = val ? ei[e] : -1;
        cols[it] = val ? ei[E + e] : 0;
    }
#pragma unroll
    for (int it = 0; it < 8; ++it)
        if (rows[it] >= 0) pos[it] = atomicAdd(&cur[rows[it]], 1);
#pragma unroll
    for (int it = 0; it < 8; ++it)
        if (rows[it] >= 0) {
            const int le = (it * 256 + tid) * 3;
            rec[pos[it]] = make_uint4((unsigned)cols[it], sR[le], sR[le + 1], sR[le + 2]);
        }
}

// ---------- kernel 4: dual MFMA GEMM, one wave per 16-row tile ----------
// mat0 -> xtb (bf16), mat1 -> hb (fp8 e4m3)
__global__ __launch_bounds__(64)
void gemm_mfma(const float* __restrict__ x, const unsigned short* __restrict__ Wb,
               const float* __restrict__ bn, const float* __restrict__ bnm,
               unsigned short* __restrict__ xtb, unsigned char* __restrict__ hb,
               int nrows) {
    const int lane = threadIdx.x;
    const int row16 = lane & 15;
    const int kgrp = lane >> 4;  // 0..3
    const int t = blockIdx.x;

    float biasA[8], biasB[8];
#pragma unroll
    for (int ct = 0; ct < 8; ++ct) {
        biasA[ct] = bn[ct * 16 + row16];
        biasB[ct] = bnm[ct * 16 + row16];
    }

    const int ra = t * 16 + row16;
    const bool rv = ra < nrows;
    short8 a[4];
#pragma unroll
    for (int s = 0; s < 4; ++s) {
        const float* xp = x + (size_t)ra * D + kgrp * 8 + 32 * s;
        float4 u0 = rv ? *reinterpret_cast<const float4*>(xp)
                       : make_float4(0.f, 0.f, 0.f, 0.f);
        float4 u1 = rv ? *reinterpret_cast<const float4*>(xp + 4)
                       : make_float4(0.f, 0.f, 0.f, 0.f);
        a[s][0] = (short)f2bf(u0.x); a[s][1] = (short)f2bf(u0.y);
        a[s][2] = (short)f2bf(u0.z); a[s][3] = (short)f2bf(u0.w);
        a[s][4] = (short)f2bf(u1.x); a[s][5] = (short)f2bf(u1.y);
        a[s][6] = (short)f2bf(u1.z); a[s][7] = (short)f2bf(u1.w);
    }
    const int rw0 = t * 16 + kgrp * 4;
#pragma unroll
    for (int mat = 0; mat < 2; ++mat) {
#pragma unroll
        for (int ct = 0; ct < 8; ++ct) {
            f32x4 acc = {0.f, 0.f, 0.f, 0.f};
#pragma unroll
            for (int s = 0; s < 4; ++s) {
                short8 bfr = *reinterpret_cast<const short8*>(
                    Wb + (size_t)((((mat * 8 + ct) * 4 + s) * 64 + lane)) * 8);
                acc = __builtin_amdgcn_mfma_f32_16x16x32_bf16(a[s], bfr, acc, 0, 0, 0);
            }
            const float bsc = mat ? biasB[ct] : biasA[ct];
            const int dcol = ct * 16 + row16;
#pragma unroll
            for (int j = 0; j < 4; ++j) {
                const int r = rw0 + j;
                if (r < nrows) {
                    if (mat == 0)
                        xtb[(size_t)r * D + dcol] = f2bf(acc[j] + bsc);
                    else
                        hb[(size_t)r * D + dcol] = (unsigned char)f2fp8(acc[j] + bsc);
                }
            }
        }
    }
}

// ---------- kernel 5: per-node gather-aggregate + residual + LayerNorm ----------
// One wave per node. Lane l owns dims 8*(l&15)..+7; quarter-wave (l>>4) owns
// edge (4t + l>>4) of each quad -> one uint2 fp8 load gathers FOUR edges' rows.
// ea/col broadcast via ds_bpermute; MLP via v_dot2_f32_bf16 on packed pairs.
__global__ __launch_bounds__(256)
void aggregate_ln(const unsigned char* __restrict__ h8,
                  const int* __restrict__ start, const int* __restrict__ cnt,
                  const uint4* __restrict__ rec,
                  const float* __restrict__ Wc, const float* __restrict__ bc,
                  const unsigned* __restrict__ xtb,
                  const float* __restrict__ gamma, const float* __restrict__ beta,
                  float* __restrict__ out, int nnode) {
    const int lane = threadIdx.x & 63;
    const int wid = threadIdx.x >> 6;
    const int d0 = (lane & 15) * 8;  // my 8 dims
    const int qsel = lane >> 4;      // my quarter

    // pack Wc pairs (bf16x2 per k-pair) + bias/gamma/beta for my dims
    unsigned wcp[3][8];
    float bcf[8], gf[8], bf[8];
#pragma unroll
    for (int p = 0; p < 3; ++p)
#pragma unroll
        for (int d = 0; d < 8; ++d) {
            unsigned lo = f2bf(Wc[(2 * p) * D + d0 + d]);
            unsigned hi = f2bf(Wc[(2 * p + 1) * D + d0 + d]);
            wcp[p][d] = lo | (hi << 16);
        }
#pragma unroll
    for (int d = 0; d < 8; ++d) {
        bcf[d] = bc[d0 + d];
        gf[d] = gamma[d0 + d];
        bf[d] = beta[d0 + d];
    }

    for (int n = blockIdx.x * 4 + wid; n < nnode; n += gridDim.x * 4) {
        const int s = start[n];
        const int c = cnt[n];
        float a8[8] = {0.f, 0.f, 0.f, 0.f, 0.f, 0.f, 0.f, 0.f};
        for (int ibase = 0; ibase < c; ibase += 64) {
            const int m = min(64, c - ibase);
            const int mq = (m + 3) >> 2;
            uint4 rc = make_uint4(0, 0, 0, 0);
            if (lane < m) rc = rec[(size_t)(s + ibase) + lane];
            auto SLOT = [&](int qj) -> int { return min(qj * 4 + qsel, m - 1) << 2; };
            auto LDQ = [&](int qj) -> uint2 {
                const unsigned col =
                    (unsigned)__builtin_amdgcn_ds_bpermute(SLOT(qj), (int)rc.x);
                return *reinterpret_cast<const uint2*>(
                    h8 + (size_t)((col << 7) | (unsigned)d0));
            };
            auto QCOMP = [&](int qj, uint2 hv) {
                const int sl = SLOT(qj);
                const unsigned b01 = (unsigned)__builtin_amdgcn_ds_bpermute(sl, (int)rc.y);
                const unsigned b23 = (unsigned)__builtin_amdgcn_ds_bpermute(sl, (int)rc.z);
                const unsigned b45 = (unsigned)__builtin_amdgcn_ds_bpermute(sl, (int)rc.w);
                f32x2 h01 = cvt2_fp8(hv.x), h23 = cvt2_fp8(hv.x >> 16);
                f32x2 h45 = cvt2_fp8(hv.y), h67 = cvt2_fp8(hv.y >> 16);
                const float hd[8] = {h01[0], h01[1], h23[0], h23[1],
                                     h45[0], h45[1], h67[0], h67[1]};
                const float keep = (qj * 4 + qsel < m) ? 1.0f : 0.0f;
#pragma unroll
                for (int d = 0; d < 8; ++d) {
                    float t = bcf[d] + hd[d];
                    t = dot2bf(b01, wcp[0][d], t);
                    t = dot2bf(b23, wcp[1][d], t);
                    t = dot2bf(b45, wcp[2][d], t);
                    a8[d] = fmaf(keep, fmaxf(t, 0.0f), a8[d]);
                }
            };
            uint2 hq0 = {0, 0}, hq1 = {0, 0}, hq2 = {0, 0}, hq3 = {0, 0};
            hq0 = LDQ(0);
            if (1 < mq) hq1 = LDQ(1);
            if (2 < mq) hq2 = LDQ(2);
            if (3 < mq) hq3 = LDQ(3);
            for (int q = 0; q < 16; q += 4) {
                if (q >= mq) break;
                { QCOMP(q + 0, hq0); if (q + 4 < mq) hq0 = LDQ(q + 4); }
                if (q + 1 < mq) { QCOMP(q + 1, hq1); if (q + 5 < mq) hq1 = LDQ(q + 5); }
                if (q + 2 < mq) { QCOMP(q + 2, hq2); if (q + 6 < mq) hq2 = LDQ(q + 6); }
                if (q + 3 < mq) { QCOMP(q + 3, hq3); if (q + 7 < mq) hq3 = LDQ(q + 7); }
            }
        }
        // merge the 4 quarter-wave partial sums (all lanes end with full sums)
#pragma unroll
        for (int d = 0; d < 8; ++d) {
            a8[d] += __shfl_xor(a8[d], 16);
            a8[d] += __shfl_xor(a8[d], 32);
        }
        const float inv = 1.0f / fmaxf((float)c, 1.0f);
        const uint4 xq = *reinterpret_cast<const uint4*>(xtb + ((size_t)n << 6) + (d0 >> 1));
        float o[8];
        o[0] = fmaf(a8[0], inv, bf_lo(xq.x)); o[1] = fmaf(a8[1], inv, bf_hi(xq.x));
        o[2] = fmaf(a8[2], inv, bf_lo(xq.y)); o[3] = fmaf(a8[3], inv, bf_hi(xq.y));
        o[4] = fmaf(a8[4], inv, bf_lo(xq.z)); o[5] = fmaf(a8[5], inv, bf_hi(xq.z));
        o[6] = fmaf(a8[6], inv, bf_lo(xq.w)); o[7] = fmaf(a8[7], inv, bf_hi(xq.w));
        float s1 = 0.f, s2 = 0.f;
#pragma unroll
        for (int d = 0; d < 8; ++d) { s1 += o[d]; s2 += o[d] * o[d]; }
#pragma unroll
        for (int off = 1; off <= 8; off <<= 1) {
            s1 += __shfl_xor(s1, off);
            s2 += __shfl_xor(s2, off);
        }
        const float mean = s1 * (1.0f / D);
        const float var = s2 * (1.0f / D) - mean * mean;
        const float rstd = rsqrtf(var + LN_EPS);
        if (lane < 16) {
            float4 r0, r1;
            r0.x = (o[0] - mean) * rstd * gf[0] + bf[0];
            r0.y = (o[1] - mean) * rstd * gf[1] + bf[1];
            r0.z = (o[2] - mean) * rstd * gf[2] + bf[2];
            r0.w = (o[3] - mean) * rstd * gf[3] + bf[3];
            r1.x = (o[4] - mean) * rstd * gf[4] + bf[4];
            r1.y = (o[5] - mean) * rstd * gf[5] + bf[5];
            r1.z = (o[6] - mean) * rstd * gf[6] + bf[6];
            r1.w = (o[7] - mean) * rstd * gf[7] + bf[7];
            float4* op = reinterpret_cast<float4*>(out + (size_t)n * D + d0);
            op[0] = r0;
            op[1] = r1;
        }
    }
}

extern "C" void kernel_launch(void* const* d_in, const int* in_sizes, int n_in,
                              void* d_out, int out_size, void* d_ws, size_t ws_size,
                              hipStream_t stream) {
    const float* x     = (const float*)d_in[0];
    const float* eattr = (const float*)d_in[1];
    const float* Wn    = (const float*)d_in[2];
    const float* bn    = (const float*)d_in[3];
    const float* We    = (const float*)d_in[4];
    const float* be    = (const float*)d_in[5];
    const float* Wm    = (const float*)d_in[6];
    const float* bm    = (const float*)d_in[7];
    const float* gamma = (const float*)d_in[8];
    const float* beta  = (const float*)d_in[9];
    const int*   ei    = (const int*)d_in[10];

    const int N = in_sizes[0] / D;
    const int E = in_sizes[10] / 2;

    char* ws = (char*)d_ws;
    unsigned short* xtb = (unsigned short*)ws; ws += (size_t)N * D * 2;
    unsigned char*  hb  = (unsigned char*)ws;  ws += (size_t)N * D;
    int* ints = (int*)ws;                      ws += (size_t)(N + 4) * 4;  // cnt, cursor
    int* cnt = ints;
    int* cursor = ints + N;
    int* cur    = (int*)ws;                    ws += (size_t)N * 4;
    int* startv = (int*)ws;                    ws += (size_t)N * 4;
    uint4* rec  = (uint4*)ws;                  ws += (size_t)E * 16;
    float* Wnm  = (float*)ws;                  ws += (size_t)D * D * 4;
    float* bnm  = (float*)ws;                  ws += (size_t)D * 4;
    float* Wc   = (float*)ws;                  ws += (size_t)EDGE_DIM * D * 4;
    float* bcv  = (float*)ws;                  ws += (size_t)D * 4;
    unsigned short* Wb = (unsigned short*)ws;  ws += (size_t)4096 * 8 * 2;

    const int nscan = (N + 1023) / 1024;
    const int ntile = (N + 15) / 16;

    hipMemsetAsync(ints, 0, (size_t)(N + 4) * 4, stream);

    setup_all<<<136 + HIST_BLOCKS, 128, 0, stream>>>(Wn, bn, We, be, Wm, bm, ei, E,
                                                     Wnm, bnm, Wc, bcv, cnt);
    scan_pack<<<nscan + 4, 1024, 0, stream>>>(cnt, startv, cur, cursor, N, nscan,
                                              Wn, Wnm, Wb);
    scatter_rec<<<(E + 2047) / 2048, 256, 0, stream>>>(ei, E, eattr, cur, rec);
    gemm_mfma<<<ntile, 64, 0, stream>>>(x, Wb, bn, bnm, xtb, hb, N);
    aggregate_ln<<<(N + 3) / 4, 256, 0, stream>>>(hb, startv, cnt, rec,
                                                  Wc, bcv, (const unsigned*)xtb,
                                                  gamma, beta, (float*)d_out, N);
}

// Round 12
// 170.245 us; speedup vs baseline: 1.0778x; 1.0778x over previous
//
#include <hip/hip_runtime.h>
#include <hip/hip_bf16.h>

#define D 128
#define EDGE_DIM 6
#define LN_EPS 1e-5f
#define HIST_BLOCKS 2048

typedef __attribute__((ext_vector_type(8))) short short8;
typedef __attribute__((ext_vector_type(4))) float f32x4;
typedef __attribute__((ext_vector_type(2))) float f32x2;

static __device__ __forceinline__ float bf_lo(unsigned u) { return __uint_as_float(u << 16); }
static __device__ __forceinline__ float bf_hi(unsigned u) { return __uint_as_float(u & 0xffff0000u); }
static __device__ __forceinline__ unsigned short f2bf(float f) {
    __hip_bfloat16 h = __float2bfloat16(f);
    return *reinterpret_cast<unsigned short*>(&h);
}

// ---------- kernel 1: fused setup ----------
// blocks 0..127: Wnm = Wn@Wm1 ; 128: bnm = bn@Wm1 ; 129..134: Wc = We@Wm2 ;
// 135: bc = be@Wm2 + bm ; >=136: histogram of edge rows.
__global__ __launch_bounds__(128)
void setup_all(const float* __restrict__ Wn, const float* __restrict__ bn,
               const float* __restrict__ We, const float* __restrict__ be,
               const float* __restrict__ Wm, const float* __restrict__ bm,
               const int* __restrict__ ei, int E,
               float* __restrict__ Wnm, float* __restrict__ bnm,
               float* __restrict__ Wc, float* __restrict__ bc,
               int* __restrict__ cnt) {
    const int b = blockIdx.x;
    const int d = threadIdx.x;
    if (b < 128) {
        float acc = 0.f;
#pragma unroll 8
        for (int j = 0; j < D; ++j)
            acc = fmaf(Wn[b * D + j], Wm[j * D + d], acc);
        Wnm[b * D + d] = acc;
    } else if (b == 128) {
        float acc = 0.f;
#pragma unroll 8
        for (int j = 0; j < D; ++j)
            acc = fmaf(bn[j], Wm[j * D + d], acc);
        bnm[d] = acc;
    } else if (b < 135) {
        const int k = b - 129;
        float acc = 0.f;
#pragma unroll 8
        for (int j = 0; j < D; ++j)
            acc = fmaf(We[k * D + j], Wm[(D + j) * D + d], acc);
        Wc[k * D + d] = acc;
    } else if (b == 135) {
        float acc = bm[d];
#pragma unroll 8
        for (int j = 0; j < D; ++j)
            acc = fmaf(be[j], Wm[(D + j) * D + d], acc);
        bc[d] = acc;
    } else {
        for (int i = (b - 136) * 128 + d; i < E; i += HIST_BLOCKS * 128)
            atomicAdd(&cnt[ei[i]], 1);
    }
}

// ---------- kernel 2: scan (blocks < nscan) + pack Wb (blocks >= nscan) ----------
__global__ __launch_bounds__(1024)
void scan_pack(const int* __restrict__ cnt, int* __restrict__ start,
               int* __restrict__ cur, int* __restrict__ cursor, int n, int nscan,
               const float* __restrict__ Wn, const float* __restrict__ Wnm,
               unsigned short* __restrict__ Wb) {
    const int tid = threadIdx.x;
    if ((int)blockIdx.x >= nscan) {
        const int idx = ((int)blockIdx.x - nscan) * 1024 + tid;  // 4096 fragments
        if (idx < 4096) {
            const int lane = idx & 63;
            const int s = (idx >> 6) & 3;
            const int ct = (idx >> 8) & 7;
            const int mat = idx >> 11;
            const float* W = mat ? Wnm : Wn;
            const int col = ct * 16 + (lane & 15);
            const int k0 = (lane >> 4) * 8 + 32 * s;
            short8 v;
#pragma unroll
            for (int j = 0; j < 8; ++j)
                v[j] = (short)f2bf(W[(size_t)(k0 + j) * D + col]);
            *reinterpret_cast<short8*>(Wb + (size_t)idx * 8) = v;
        }
        return;
    }
    __shared__ int wsum[16];
    __shared__ int sbase;
    const int lane = tid & 63, wid = tid >> 6;
    const int i = blockIdx.x * 1024 + tid;
    const int v = (i < n) ? cnt[i] : 0;
    int x = v;
#pragma unroll
    for (int off = 1; off < 64; off <<= 1) {
        int t = __shfl_up(x, off);
        if (lane >= off) x += t;
    }
    if (lane == 63) wsum[wid] = x;
    __syncthreads();
    if (wid == 0) {
        int w = (lane < 16) ? wsum[lane] : 0;
#pragma unroll
        for (int off = 1; off < 16; off <<= 1) {
            int t = __shfl_up(w, off);
            if (lane >= off) w += t;
        }
        if (lane < 16) wsum[lane] = w;
    }
    __syncthreads();
    const int total = wsum[15];
    if (tid == 0) sbase = atomicAdd(cursor, total);
    __syncthreads();
    const int woff = (wid > 0) ? wsum[wid - 1] : 0;
    if (i < n) {
        const int sv = sbase + woff + x - v;
        start[i] = sv;
        cur[i] = sv;
    }
}

// ---------- kernel 3: FUSED scatter (blocks < nscat) + dual MFMA GEMM ----------
// The two halves are independent (both depend only on scan_pack outputs);
// scatter is latency-bound (VALU ~1%), gemm is MFMA-bound -> co-scheduling
// overlaps them on the CUs. Scatter blocks placed first to start early.
__global__ __launch_bounds__(256)
void scat_gemm(const int* __restrict__ ei, int E, const float* __restrict__ ea,
               int* __restrict__ cur, uint4* __restrict__ rec, int nscat,
               const float* __restrict__ x, const unsigned short* __restrict__ Wb,
               const float* __restrict__ bn, const float* __restrict__ bnm,
               unsigned short* __restrict__ xtb, unsigned short* __restrict__ hb,
               int nrows) {
    __shared__ unsigned sR[2048 * 3];  // 24 KB, used by scatter blocks only
    const int tid = threadIdx.x;
    if ((int)blockIdx.x < nscat) {
        // ----- scatter: 2048 edges/block, 8 edges/thread, batched atomics -----
        const int base = blockIdx.x * 2048;
        const int nrec = min(2048, E - base);
        const float2* ea2 = reinterpret_cast<const float2*>(ea);
        for (int i = tid; i < nrec * 3; i += 256) {
            float2 p = ea2[(size_t)base * 3 + i];
            sR[i] = (unsigned)f2bf(p.x) | ((unsigned)f2bf(p.y) << 16);
        }
        __syncthreads();
        int rows[8], cols[8], pos[8];
#pragma unroll
        for (int it = 0; it < 8; ++it) {
            const int e = base + it * 256 + tid;
            const bool val = e < E;
            rows[it] = val ? ei[e] : -1;
            cols[it] = val ? ei[E + e] : 0;
        }
#pragma unroll
        for (int it = 0; it < 8; ++it)
            if (rows[it] >= 0) pos[it] = atomicAdd(&cur[rows[it]], 1);
#pragma unroll
        for (int it = 0; it < 8; ++it)
            if (rows[it] >= 0) {
                const int le = (it * 256 + tid) * 3;
                rec[pos[it]] = make_uint4((unsigned)cols[it], sR[le], sR[le + 1], sR[le + 2]);
            }
        return;
    }
    // ----- dual MFMA GEMM: 4 waves/block, one 16-row tile per wave -----
    const int ntile = (nrows + 15) / 16;
    const int lane = tid & 63;
    const int wid = tid >> 6;
    const int t = ((int)blockIdx.x - nscat) * 4 + wid;
    if (t >= ntile) return;
    const int row16 = lane & 15;
    const int kgrp = lane >> 4;  // 0..3

    float biasA[8], biasB[8];
#pragma unroll
    for (int ct = 0; ct < 8; ++ct) {
        biasA[ct] = bn[ct * 16 + row16];
        biasB[ct] = bnm[ct * 16 + row16];
    }

    const int ra = t * 16 + row16;
    const bool rv = ra < nrows;
    short8 a[4];
#pragma unroll
    for (int s = 0; s < 4; ++s) {
        const float* xp = x + (size_t)ra * D + kgrp * 8 + 32 * s;
        float4 u0 = rv ? *reinterpret_cast<const float4*>(xp)
                       : make_float4(0.f, 0.f, 0.f, 0.f);
        float4 u1 = rv ? *reinterpret_cast<const float4*>(xp + 4)
                       : make_float4(0.f, 0.f, 0.f, 0.f);
        a[s][0] = (short)f2bf(u0.x); a[s][1] = (short)f2bf(u0.y);
        a[s][2] = (short)f2bf(u0.z); a[s][3] = (short)f2bf(u0.w);
        a[s][4] = (short)f2bf(u1.x); a[s][5] = (short)f2bf(u1.y);
        a[s][6] = (short)f2bf(u1.z); a[s][7] = (short)f2bf(u1.w);
    }
    const int rw0 = t * 16 + kgrp * 4;
#pragma unroll
    for (int mat = 0; mat < 2; ++mat) {
        unsigned short* out = mat ? hb : xtb;
#pragma unroll
        for (int ct = 0; ct < 8; ++ct) {
            f32x4 acc = {0.f, 0.f, 0.f, 0.f};
#pragma unroll
            for (int s = 0; s < 4; ++s) {
                short8 bfr = *reinterpret_cast<const short8*>(
                    Wb + (size_t)((((mat * 8 + ct) * 4 + s) * 64 + lane)) * 8);
                acc = __builtin_amdgcn_mfma_f32_16x16x32_bf16(a[s], bfr, acc, 0, 0, 0);
            }
            const float bsc = mat ? biasB[ct] : biasA[ct];
            const int dcol = ct * 16 + row16;
#pragma unroll
            for (int j = 0; j < 4; ++j) {
                const int r = rw0 + j;
                if (r < nrows) out[(size_t)r * D + dcol] = f2bf(acc[j] + bsc);
            }
        }
    }
}

// ---------- kernel 4: per-node gather-aggregate + residual + LayerNorm ----------
// (R10 version — proven 63us floor.) One wave per node; lane holds dims (2l,2l+1).
__global__ __launch_bounds__(256)
void aggregate_ln(const unsigned* __restrict__ h,
                  const int* __restrict__ start, const int* __restrict__ cnt,
                  const uint4* __restrict__ rec,
                  const float* __restrict__ Wc, const float* __restrict__ bc,
                  const unsigned* __restrict__ xtb,
                  const float* __restrict__ gamma, const float* __restrict__ beta,
                  float* __restrict__ out, int nnode) {
    const int lane = threadIdx.x & 63;
    const int wid = threadIdx.x >> 6;

    f32x2 wc[EDGE_DIM];
#pragma unroll
    for (int k = 0; k < EDGE_DIM; ++k)
        wc[k] = reinterpret_cast<const f32x2*>(Wc)[k * 64 + lane];
    const f32x2 bc2 = reinterpret_cast<const f32x2*>(bc)[lane];
    const f32x2 g = reinterpret_cast<const f32x2*>(gamma)[lane];
    const f32x2 bb = reinterpret_cast<const f32x2*>(beta)[lane];

    for (int n = blockIdx.x * 4 + wid; n < nnode; n += gridDim.x * 4) {
        const int s = start[n];
        const int c = cnt[n];
        const unsigned xu = xtb[(unsigned)(n * 64 + lane)];
        f32x2 axy = {0.f, 0.f};
        for (int ibase = 0; ibase < c; ibase += 64) {
            const int m = min(64, c - ibase);
            uint4 rc = make_uint4(0, 0, 0, 0);
            if (lane < m) rc = rec[(size_t)(s + ibase) + lane];
            auto LDH = [&](int j) -> unsigned {
                const int jc = min(j, m - 1);
                const unsigned colj = (unsigned)__builtin_amdgcn_readlane((int)rc.x, jc);
                const unsigned* hrow = h + ((size_t)colj << 6);
                return hrow[lane];
            };
            auto COMP = [&](int j, unsigned hv) {
                const unsigned b01 = (unsigned)__builtin_amdgcn_readlane((int)rc.y, j);
                const unsigned b23 = (unsigned)__builtin_amdgcn_readlane((int)rc.z, j);
                const unsigned b45 = (unsigned)__builtin_amdgcn_readlane((int)rc.w, j);
                f32x2 e01, e23, e45, hx, mA, mB;
                e01[0] = bf_lo(b01); e01[1] = bf_hi(b01);
                e23[0] = bf_lo(b23); e23[1] = bf_hi(b23);
                e45[0] = bf_lo(b45); e45[1] = bf_hi(b45);
                hx[0] = bf_lo(hv); hx[1] = bf_hi(hv);
                asm("v_pk_add_f32 %0, %1, %2" : "=v"(mA) : "v"(bc2), "v"(hx));
                asm("v_pk_mul_f32 %0, %1, %2 op_sel:[1,0] op_sel_hi:[1,1]"
                    : "=v"(mB) : "s"(e01), "v"(wc[1]));
                asm("v_pk_fma_f32 %0, %1, %2, %0 op_sel:[0,0,0] op_sel_hi:[0,1,1]"
                    : "+v"(mA) : "s"(e01), "v"(wc[0]));
                asm("v_pk_fma_f32 %0, %1, %2, %0 op_sel:[1,0,0] op_sel_hi:[1,1,1]"
                    : "+v"(mB) : "s"(e23), "v"(wc[3]));
                asm("v_pk_fma_f32 %0, %1, %2, %0 op_sel:[0,0,0] op_sel_hi:[0,1,1]"
                    : "+v"(mA) : "s"(e23), "v"(wc[2]));
                asm("v_pk_fma_f32 %0, %1, %2, %0 op_sel:[1,0,0] op_sel_hi:[1,1,1]"
                    : "+v"(mB) : "s"(e45), "v"(wc[5]));
                asm("v_pk_fma_f32 %0, %1, %2, %0 op_sel:[0,0,0] op_sel_hi:[0,1,1]"
                    : "+v"(mA) : "s"(e45), "v"(wc[4]));
                asm("v_pk_add_f32 %0, %0, %1" : "+v"(mA) : "v"(mB));
                axy[0] += fmaxf(mA[0], 0.f);
                axy[1] += fmaxf(mA[1], 0.f);
            };
            unsigned h0 = LDH(0), h1 = LDH(1), h2 = LDH(2), h3 = LDH(3),
                     h4 = LDH(4), h5 = LDH(5), h6 = LDH(6), h7 = LDH(7);
            int i = 0;
            for (; i + 8 <= m; i += 8) {
                COMP(i + 0, h0); h0 = LDH(i + 8);
                COMP(i + 1, h1); h1 = LDH(i + 9);
                COMP(i + 2, h2); h2 = LDH(i + 10);
                COMP(i + 3, h3); h3 = LDH(i + 11);
                COMP(i + 4, h4); h4 = LDH(i + 12);
                COMP(i + 5, h5); h5 = LDH(i + 13);
                COMP(i + 6, h6); h6 = LDH(i + 14);
                COMP(i + 7, h7); h7 = LDH(i + 15);
            }
            if (i + 0 < m) COMP(i + 0, h0);
            if (i + 1 < m) COMP(i + 1, h1);
            if (i + 2 < m) COMP(i + 2, h2);
            if (i + 3 < m) COMP(i + 3, h3);
            if (i + 4 < m) COMP(i + 4, h4);
            if (i + 5 < m) COMP(i + 5, h5);
            if (i + 6 < m) COMP(i + 6, h6);
        }
        const float inv = 1.0f / fmaxf((float)c, 1.0f);
        float o0 = fmaf(axy[0], inv, bf_lo(xu));
        float o1 = fmaf(axy[1], inv, bf_hi(xu));
        float s1 = o0 + o1, s2 = o0 * o0 + o1 * o1;
#pragma unroll
        for (int off = 32; off; off >>= 1) {
            s1 += __shfl_xor(s1, off);
            s2 += __shfl_xor(s2, off);
        }
        const float mean = s1 * (1.0f / D);
        const float var = s2 * (1.0f / D) - mean * mean;
        const float rstd = rsqrtf(var + LN_EPS);
        float2 r;
        r.x = (o0 - mean) * rstd * g[0] + bb[0];
        r.y = (o1 - mean) * rstd * g[1] + bb[1];
        reinterpret_cast<float2*>(out)[(size_t)n * 64 + lane] = r;
    }
}

extern "C" void kernel_launch(void* const* d_in, const int* in_sizes, int n_in,
                              void* d_out, int out_size, void* d_ws, size_t ws_size,
                              hipStream_t stream) {
    const float* x     = (const float*)d_in[0];
    const float* eattr = (const float*)d_in[1];
    const float* Wn    = (const float*)d_in[2];
    const float* bn    = (const float*)d_in[3];
    const float* We    = (const float*)d_in[4];
    const float* be    = (const float*)d_in[5];
    const float* Wm    = (const float*)d_in[6];
    const float* bm    = (const float*)d_in[7];
    const float* gamma = (const float*)d_in[8];
    const float* beta  = (const float*)d_in[9];
    const int*   ei    = (const int*)d_in[10];

    const int N = in_sizes[0] / D;
    const int E = in_sizes[10] / 2;

    char* ws = (char*)d_ws;
    unsigned short* xtb = (unsigned short*)ws; ws += (size_t)N * D * 2;
    unsigned short* hb  = (unsigned short*)ws; ws += (size_t)N * D * 2;
    int* ints = (int*)ws;                      ws += (size_t)(N + 4) * 4;  // cnt, cursor
    int* cnt = ints;
    int* cursor = ints + N;
    int* cur    = (int*)ws;                    ws += (size_t)N * 4;
    int* startv = (int*)ws;                    ws += (size_t)N * 4;
    uint4* rec  = (uint4*)ws;                  ws += (size_t)E * 16;
    float* Wnm  = (float*)ws;                  ws += (size_t)D * D * 4;
    float* bnm  = (float*)ws;                  ws += (size_t)D * 4;
    float* Wc   = (float*)ws;                  ws += (size_t)EDGE_DIM * D * 4;
    float* bcv  = (float*)ws;                  ws += (size_t)D * 4;
    unsigned short* Wb = (unsigned short*)ws;  ws += (size_t)4096 * 8 * 2;

    const int nscan = (N + 1023) / 1024;
    const int nscat = (E + 2047) / 2048;
    const int ntile = (N + 15) / 16;

    hipMemsetAsync(ints, 0, (size_t)(N + 4) * 4, stream);

    setup_all<<<136 + HIST_BLOCKS, 128, 0, stream>>>(Wn, bn, We, be, Wm, bm, ei, E,
                                                     Wnm, bnm, Wc, bcv, cnt);
    scan_pack<<<nscan + 4, 1024, 0, stream>>>(cnt, startv, cur, cursor, N, nscan,
                                              Wn, Wnm, Wb);
    scat_gemm<<<nscat + (ntile + 3) / 4, 256, 0, stream>>>(ei, E, eattr, cur, rec, nscat,
                                                           x, Wb, bn, bnm, xtb, hb, N);
    aggregate_ln<<<(N + 3) / 4, 256, 0, stream>>>((const unsigned*)hb, startv, cnt, rec,
                                                  Wc, bcv, (const unsigned*)xtb,
                                                  gamma, beta, (float*)d_out, N);
}